// Round 1
// baseline (314.705 us; speedup 1.0000x reference)
//
#include <hip/hip_runtime.h>

// SoftTopK: x (8,1024,256) f32, noise (8,1024,8,256) f32
// perturbed = x + noise*1e-4 ; idx = smallest-16 indices (stable) per (b,n,s)
// out (8,1024,16,256) f32 = one_hot(idx).mean over s
//
// One block per (b,n). 4 waves x 2 samples each. 4 elems/lane (float4).
// Selection: 16x wave-wide u64 min-reduce over keys (monotone(v)<<32)|m,
// which is exact lexicographic (value asc, index asc) -- matches lax.top_k
// stable tie-break. __fadd_rn/__fmul_rn forbid FMA contraction so the
// perturbed values bit-match the fp32 reference.

#define TOPK 16
#define NSAMP 8
#define MDIM 256
#define BN_TOTAL 8192

__device__ __forceinline__ unsigned long long make_key(float v, unsigned m) {
  unsigned b = __float_as_uint(v);
  // monotone map: ascending u <=> ascending v (total order, -inf..+inf)
  unsigned u = (b & 0x80000000u) ? ~b : (b | 0x80000000u);
  return (((unsigned long long)u) << 32) | (unsigned long long)m;
}

__global__ __launch_bounds__(256) void soft_topk_kernel(
    const float* __restrict__ x, const float* __restrict__ noise,
    float* __restrict__ out) {
  const int bn = blockIdx.x;
  const int tid = threadIdx.x;
  const int wave = tid >> 6;
  const int lane = tid & 63;

  __shared__ __align__(16) float counts[TOPK * MDIM];  // 16 KiB
#pragma unroll
  for (int i = 0; i < TOPK; ++i) counts[tid + MDIM * i] = 0.0f;
  __syncthreads();

  const int mbase = lane * 4;
  const float4 x4 =
      *reinterpret_cast<const float4*>(x + (size_t)bn * MDIM + mbase);

  for (int si = 0; si < 2; ++si) {
    const int s = wave * 2 + si;
    const float4 n4 = *reinterpret_cast<const float4*>(
        noise + ((size_t)bn * NSAMP + s) * MDIM + mbase);

    // no-contract: bit-match reference's (x + noise*sigma) in fp32
    const float v0 = __fadd_rn(x4.x, __fmul_rn(n4.x, 1e-4f));
    const float v1 = __fadd_rn(x4.y, __fmul_rn(n4.y, 1e-4f));
    const float v2 = __fadd_rn(x4.z, __fmul_rn(n4.z, 1e-4f));
    const float v3 = __fadd_rn(x4.w, __fmul_rn(n4.w, 1e-4f));

    unsigned long long k0 = make_key(v0, mbase + 0);
    unsigned long long k1 = make_key(v1, mbase + 1);
    unsigned long long k2 = make_key(v2, mbase + 2);
    unsigned long long k3 = make_key(v3, mbase + 3);

    unsigned cap = 0;  // m captured by lane==rank
#pragma unroll
    for (int it = 0; it < TOPK; ++it) {
      unsigned long long a = k0 < k1 ? k0 : k1;
      unsigned long long b = k2 < k3 ? k2 : k3;
      unsigned long long lm = a < b ? a : b;
      // butterfly min-reduce: all lanes end with global min
#pragma unroll
      for (int d = 1; d < 64; d <<= 1) {
        unsigned long long o = __shfl_xor(lm, d, 64);
        lm = o < lm ? o : lm;
      }
      if (lane == it) cap = (unsigned)lm;  // low 32 bits = m
      if (it < TOPK - 1) {
        k0 = (k0 == lm) ? ~0ull : k0;
        k1 = (k1 == lm) ? ~0ull : k1;
        k2 = (k2 == lm) ? ~0ull : k2;
        k3 = (k3 == lm) ? ~0ull : k3;
      }
    }
    if (lane < TOPK) atomicAdd(&counts[lane * MDIM + cap], 0.125f);
  }
  __syncthreads();

  // write 16x256 floats, coalesced float4
  float4* outv = reinterpret_cast<float4*>(out + (size_t)bn * (TOPK * MDIM));
  const float4* cv = reinterpret_cast<const float4*>(counts);
#pragma unroll
  for (int i = 0; i < 4; ++i) outv[tid + 256 * i] = cv[tid + 256 * i];
}

extern "C" void kernel_launch(void* const* d_in, const int* in_sizes, int n_in,
                              void* d_out, int out_size, void* d_ws,
                              size_t ws_size, hipStream_t stream) {
  const float* x = (const float*)d_in[0];
  const float* noise = (const float*)d_in[1];
  float* out = (float*)d_out;
  soft_topk_kernel<<<BN_TOTAL, 256, 0, stream>>>(x, noise, out);
}

// Round 2
// 202.298 us; speedup vs baseline: 1.5556x; 1.5556x over previous
//
#include <hip/hip_runtime.h>

// SoftTopK: x (8,1024,256) f32, noise (8,1024,8,256) f32
// perturbed = x + noise*1e-4 ; idx = smallest-16 indices (stable) per (b,n,s)
// out (8,1024,16,256) f32 = one_hot(idx).mean over s
//
// One block per (b,n). 4 waves x 2 samples each. 4 elems/lane (float4).
// Selection per sample: 16 rounds; each round min-reduces the 32-bit
// monotone value key across 64 lanes using DPP (xor1,xor2,~xor4,~xor8)
// + ds_swizzle (xor16) + bpermute (xor32), then resolves the winning
// index exactly via ballot+ctz (lowest lane) and the per-lane slot
// tracked with <= (lowest slot). This reproduces lax.top_k's stable
// (value asc, index asc) order bit-exactly. __fadd_rn/__fmul_rn forbid
// FMA contraction so perturbed values bit-match the fp32 reference.

#define TOPK 16
#define NSAMP 8
#define MDIM 256
#define BN_TOTAL 8192

__device__ __forceinline__ unsigned mono(float v) {
  unsigned b = __float_as_uint(v);
  // monotone map: ascending u <=> ascending v (total order)
  return (b & 0x80000000u) ? ~b : (b | 0x80000000u);
}

template <int CTRL>
__device__ __forceinline__ unsigned dpp_min_step(unsigned v) {
  unsigned o = (unsigned)__builtin_amdgcn_update_dpp((int)v, (int)v, CTRL,
                                                     0xF, 0xF, false);
  return o < v ? o : v;
}

__global__ __launch_bounds__(256) void soft_topk_kernel(
    const float* __restrict__ x, const float* __restrict__ noise,
    float* __restrict__ out) {
  const int bn = blockIdx.x;
  const int tid = threadIdx.x;
  const int wave = tid >> 6;
  const int lane = tid & 63;

  __shared__ __align__(16) float counts[TOPK * MDIM];  // 16 KiB
  {
    float4* cz = reinterpret_cast<float4*>(counts);
#pragma unroll
    for (int i = 0; i < 4; ++i)
      cz[tid + 256 * i] = make_float4(0.f, 0.f, 0.f, 0.f);
  }
  __syncthreads();

  const int mbase = lane * 4;
  const float4 x4 =
      *reinterpret_cast<const float4*>(x + (size_t)bn * MDIM + mbase);

  for (int si = 0; si < 2; ++si) {
    const int s = wave * 2 + si;
    const float4 n4 = *reinterpret_cast<const float4*>(
        noise + ((size_t)bn * NSAMP + s) * MDIM + mbase);

    // no-contract: bit-match reference's (x + noise*sigma) in fp32
    unsigned k0 = mono(__fadd_rn(x4.x, __fmul_rn(n4.x, 1e-4f)));
    unsigned k1 = mono(__fadd_rn(x4.y, __fmul_rn(n4.y, 1e-4f)));
    unsigned k2 = mono(__fadd_rn(x4.z, __fmul_rn(n4.z, 1e-4f)));
    unsigned k3 = mono(__fadd_rn(x4.w, __fmul_rn(n4.w, 1e-4f)));

    unsigned cap = 0;  // m captured by lane==rank
#pragma unroll
    for (int it = 0; it < TOPK; ++it) {
      // per-lane min + slot, <= prefers lower slot (stable)
      const bool c01 = k0 <= k1;
      const unsigned a = c01 ? k0 : k1;
      const unsigned sa = c01 ? 0u : 1u;
      const bool c23 = k2 <= k3;
      const unsigned b = c23 ? k2 : k3;
      const unsigned sb = c23 ? 2u : 3u;
      const bool cab = a <= b;
      const unsigned lmin = cab ? a : b;
      const unsigned lslot = cab ? sa : sb;

      // 64-lane butterfly min, DPP for intra-row stages
      unsigned gm = lmin;
      gm = dpp_min_step<0xB1>(gm);   // quad_perm [1,0,3,2] : xor1
      gm = dpp_min_step<0x4E>(gm);   // quad_perm [2,3,0,1] : xor2
      gm = dpp_min_step<0x141>(gm);  // row_half_mirror (~xor4 here)
      gm = dpp_min_step<0x140>(gm);  // row_mirror (~xor8 here)
      {
        unsigned o = (unsigned)__builtin_amdgcn_ds_swizzle((int)gm, 0x401F);
        gm = o < gm ? o : gm;  // xor16 (within 32-lane groups)
      }
      {
        unsigned o = (unsigned)__shfl_xor((int)gm, 32, 64);
        gm = o < gm ? o : gm;  // xor32
      }

      // winner = lowest lane whose local min equals the global min,
      // then its lowest slot -> exactly the smallest (value, m)
      const unsigned long long mask = __ballot(lmin == gm);
      const int wl = __ffsll(mask) - 1;
      const unsigned wslot =
          (unsigned)__builtin_amdgcn_readlane((int)lslot, wl);
      const unsigned m_win = ((unsigned)wl << 2) | wslot;

      if (lane == it) cap = m_win;

      if (it < TOPK - 1) {
        if (lane == wl) {  // invalidate exactly the extracted slot
          if (wslot == 0u) k0 = 0xFFFFFFFFu;
          else if (wslot == 1u) k1 = 0xFFFFFFFFu;
          else if (wslot == 2u) k2 = 0xFFFFFFFFu;
          else k3 = 0xFFFFFFFFu;
        }
      }
    }
    if (lane < TOPK) atomicAdd(&counts[lane * MDIM + cap], 0.125f);
  }
  __syncthreads();

  // write 16x256 floats, coalesced float4
  float4* outv = reinterpret_cast<float4*>(out + (size_t)bn * (TOPK * MDIM));
  const float4* cv = reinterpret_cast<const float4*>(counts);
#pragma unroll
  for (int i = 0; i < 4; ++i) outv[tid + 256 * i] = cv[tid + 256 * i];
}

extern "C" void kernel_launch(void* const* d_in, const int* in_sizes, int n_in,
                              void* d_out, int out_size, void* d_ws,
                              size_t ws_size, hipStream_t stream) {
  const float* x = (const float*)d_in[0];
  const float* noise = (const float*)d_in[1];
  float* out = (float*)d_out;
  soft_topk_kernel<<<BN_TOTAL, 256, 0, stream>>>(x, noise, out);
}

// Round 4
// 201.481 us; speedup vs baseline: 1.5620x; 1.0041x over previous
//
#include <hip/hip_runtime.h>

// SoftTopK: x (8,1024,256) f32, noise (8,1024,8,256) f32
// perturbed = x + noise*1e-4 ; idx = smallest-16 indices (stable) per (b,n,s)
// out (8,1024,16,256) f32 = one_hot(idx).mean over s
//
// One block per (b,n). 8 waves, one sample per wave. 4 elems/lane (float4).
// Selection per sample: 16 rounds; each round min-reduces the 32-bit
// monotone value key across 64 lanes using a pure-DPP cascade
// (xor1, xor2, row_half_mirror, row_mirror, row_bcast15, row_bcast31 ->
// lane 63 holds the global min -> readlane to SGPR). Winner index
// resolved exactly via ballot+ctz (lowest lane) and lowest slot -- this
// reproduces lax.top_k's stable (value asc, index asc) order bit-exactly.
// __fadd_rn/__fmul_rn forbid FMA contraction so perturbed values
// bit-match the fp32 reference.

#define TOPK 16
#define NSAMP 8
#define MDIM 256
#define BN_TOTAL 8192

__device__ __forceinline__ unsigned mono(float v) {
  unsigned b = __float_as_uint(v);
  // monotone map: ascending u <=> ascending v (total order)
  return (b & 0x80000000u) ? ~b : (b | 0x80000000u);
}

template <int CTRL>
__device__ __forceinline__ unsigned dpp_min_step(unsigned v) {
  unsigned o = (unsigned)__builtin_amdgcn_update_dpp((int)v, (int)v, CTRL,
                                                     0xF, 0xF, false);
  return o < v ? o : v;
}

__global__ __launch_bounds__(512) void soft_topk_kernel(
    const float* __restrict__ x, const float* __restrict__ noise,
    float* __restrict__ out) {
  const int bn = blockIdx.x;
  const int tid = threadIdx.x;
  const int s = tid >> 6;  // wave = sample
  const int lane = tid & 63;

  __shared__ __align__(16) float counts[TOPK * MDIM];  // 16 KiB
  {
    float4* cz = reinterpret_cast<float4*>(counts);
#pragma unroll
    for (int i = 0; i < 2; ++i)
      cz[tid + 512 * i] = make_float4(0.f, 0.f, 0.f, 0.f);
  }
  __syncthreads();

  const int mbase = lane * 4;
  const float4 x4 =
      *reinterpret_cast<const float4*>(x + (size_t)bn * MDIM + mbase);
  const float4 n4 = *reinterpret_cast<const float4*>(
      noise + ((size_t)bn * NSAMP + s) * MDIM + mbase);

  // no-contract: bit-match reference's (x + noise*sigma) in fp32
  unsigned k0 = mono(__fadd_rn(x4.x, __fmul_rn(n4.x, 1e-4f)));
  unsigned k1 = mono(__fadd_rn(x4.y, __fmul_rn(n4.y, 1e-4f)));
  unsigned k2 = mono(__fadd_rn(x4.z, __fmul_rn(n4.z, 1e-4f)));
  unsigned k3 = mono(__fadd_rn(x4.w, __fmul_rn(n4.w, 1e-4f)));

  unsigned cap = 0;  // m captured by lane==rank
#pragma unroll
  for (int it = 0; it < TOPK; ++it) {
    // per-lane min + slot, <= prefers lower slot (stable)
    const bool c01 = k0 <= k1;
    const unsigned a = c01 ? k0 : k1;
    const unsigned sa = c01 ? 0u : 1u;
    const bool c23 = k2 <= k3;
    const unsigned b = c23 ? k2 : k3;
    const unsigned sb = c23 ? 2u : 3u;
    const bool cab = a <= b;
    const unsigned lmin = cab ? a : b;
    const unsigned lslot = cab ? sa : sb;

    // 64-lane min via pure-DPP cascade; lane 63 ends with global min
    unsigned gm = lmin;
    gm = dpp_min_step<0xB1>(gm);   // quad_perm [1,0,3,2] : xor1
    gm = dpp_min_step<0x4E>(gm);   // quad_perm [2,3,0,1] : xor2
    gm = dpp_min_step<0x141>(gm);  // row_half_mirror : min over 8
    gm = dpp_min_step<0x140>(gm);  // row_mirror      : min over 16
    gm = dpp_min_step<0x142>(gm);  // row_bcast15     : min over 32 (in 16-31,48-63)
    gm = dpp_min_step<0x143>(gm);  // row_bcast31     : min over 64 (in 48-63)
    const unsigned gmin = (unsigned)__builtin_amdgcn_readlane((int)gm, 63);

    // winner = lowest lane whose local min equals the global min,
    // then its lowest slot -> exactly the smallest (value, m)
    const unsigned long long mask = __ballot(lmin == gmin);
    const int wl = __ffsll(mask) - 1;
    const unsigned wslot =
        (unsigned)__builtin_amdgcn_readlane((int)lslot, wl);
    const unsigned m_win = ((unsigned)wl << 2) | wslot;

    if (lane == it) cap = m_win;

    if (it < TOPK - 1) {
      if (lane == wl) {  // invalidate exactly the extracted slot
        if (wslot == 0u) k0 = 0xFFFFFFFFu;
        else if (wslot == 1u) k1 = 0xFFFFFFFFu;
        else if (wslot == 2u) k2 = 0xFFFFFFFFu;
        else k3 = 0xFFFFFFFFu;
      }
    }
  }
  if (lane < TOPK) atomicAdd(&counts[lane * MDIM + cap], 0.125f);
  __syncthreads();

  // write 16x256 floats, coalesced float4
  float4* outv = reinterpret_cast<float4*>(out + (size_t)bn * (TOPK * MDIM));
  const float4* cv = reinterpret_cast<const float4*>(counts);
#pragma unroll
  for (int i = 0; i < 2; ++i) outv[tid + 512 * i] = cv[tid + 512 * i];
}

extern "C" void kernel_launch(void* const* d_in, const int* in_sizes, int n_in,
                              void* d_out, int out_size, void* d_ws,
                              size_t ws_size, hipStream_t stream) {
  const float* x = (const float*)d_in[0];
  const float* noise = (const float*)d_in[1];
  float* out = (float*)d_out;
  soft_topk_kernel<<<BN_TOTAL, 512, 0, stream>>>(x, noise, out);
}